// Round 2
// baseline (416.810 us; speedup 1.0000x reference)
//
#include <hip/hip_runtime.h>
#include <stdint.h>
#include <stddef.h>

#define K_DIM 4096
#define N_DIM 4096
#define BM 128
#define BN 128
#define BK 64

typedef int v4i __attribute__((ext_vector_type(4)));

__device__ __forceinline__ void load_lds16(const void* gp, void* lp) {
  __builtin_amdgcn_global_load_lds(
      (__attribute__((address_space(1))) void*)(uintptr_t)gp,
      (__attribute__((address_space(3))) void*)(uintptr_t)lp,
      16, 0, 0);
}

// ---------------- Kernel 0: pack weight int32 -> int8 ----------------------
// Harness materializes integer inputs as int32 on device; repack to int8 once
// per launch. 16 B load / 4 B store per lane.
__global__ __launch_bounds__(256) void pack_w_kernel(
    const int* __restrict__ w32, uint32_t* __restrict__ w8, int n4) {
  int i = blockIdx.x * 256 + threadIdx.x;
  if (i >= n4) return;
  int4 v = ((const int4*)w32)[i];
  w8[i] = (uint32_t)(uint8_t)v.x | ((uint32_t)(uint8_t)v.y << 8) |
          ((uint32_t)(uint8_t)v.z << 16) | ((uint32_t)(uint8_t)v.w << 24);
}

// ---------------- Kernel 1: quantize fp32 -> int8 --------------------------
// y = clip(rint(x / 0.05f), -128, 127)  (exact-rounded division + RNE, matches
// jnp.round(x / INPUT_SCALE) bit-for-bit). float4 loads (16B/lane), dword store.
__global__ __launch_bounds__(256) void quant_kernel(
    const float* __restrict__ x, uint32_t* __restrict__ xq, int n4) {
  int i = blockIdx.x * 256 + threadIdx.x;
  if (i >= n4) return;
  float4 v = ((const float4*)x)[i];
  float r0 = rintf(v.x / 0.05f);
  float r1 = rintf(v.y / 0.05f);
  float r2 = rintf(v.z / 0.05f);
  float r3 = rintf(v.w / 0.05f);
  r0 = fminf(fmaxf(r0, -128.f), 127.f);
  r1 = fminf(fmaxf(r1, -128.f), 127.f);
  r2 = fminf(fmaxf(r2, -128.f), 127.f);
  r3 = fminf(fmaxf(r3, -128.f), 127.f);
  uint32_t b0 = (uint32_t)(uint8_t)(int)r0;
  uint32_t b1 = (uint32_t)(uint8_t)(int)r1;
  uint32_t b2 = (uint32_t)(uint8_t)(int)r2;
  uint32_t b3 = (uint32_t)(uint8_t)(int)r3;
  xq[i] = b0 | (b1 << 8) | (b2 << 16) | (b3 << 24);
}

// ---------------- Kernel 2: int8 GEMM, A[M,K] x B[N,K]^T -------------------
// m97-ladder structure: 128x128 tile, BK=64, 4 waves in 2x2, each wave 4x4
// tiles of v_mfma_i32_16x16x64_i8. global_load_lds width=16 staging.
// LDS layout: row-major [128][64] int8 (row = M-row of A / N-row of B).
// A-frag (lane l): A[m = l&15][k = (l>>4)*16 .. +16)  -> ds_read_b128
// B-frag (lane l): B[k = (l>>4)*16 .. +16)][n = l&15] = w[n][k] -> ds_read_b128
// C/D: col = lane&15, row = (lane>>4)*4 + reg (dtype-independent, m121-m128)
__global__ __launch_bounds__(256) void gemm_i8_kernel(
    const int8_t* __restrict__ A,     // [M, K] quantized activations
    const int8_t* __restrict__ B,     // [N, K] weight (packed int8)
    const float* __restrict__ bias,   // [N]
    float* __restrict__ C,            // [M, N]
    int M) {
  __shared__ __align__(16) int8_t lds_a[BM * BK];  // 8 KB
  __shared__ __align__(16) int8_t lds_b[BN * BK];  // 8 KB

  const int tid  = threadIdx.x;
  const int lane = tid & 63;
  const int wave = tid >> 6;
  const int wm   = wave >> 1;    // 0..1 : wave's 64-row block of M-tile
  const int wn   = wave & 1;     // 0..1 : wave's 64-col block of N-tile
  const int quad = lane >> 4;    // 0..3
  const int lrow = lane & 15;

  const int m0 = blockIdx.y * BM;
  const int n0 = blockIdx.x * BN;

  // Staging: 8192 B per tile = 512 chunks of 16 B = 2 issues x 256 threads.
  // chunk idx -> row = idx>>2, kcol = (idx&3)*16; LDS dst = idx*16
  // (wave-uniform base + lane*16, as global_load_lds requires).
  const int r0i = tid >> 2;
  const int c0i = (tid & 3) * 16;
  const int r1i = r0i + 64;               // (tid+256)>>2
  const int8_t* a_g0 = A + (size_t)(m0 + r0i) * K_DIM + c0i;
  const int8_t* a_g1 = A + (size_t)(m0 + r1i) * K_DIM + c0i;
  const int8_t* b_g0 = B + (size_t)(n0 + r0i) * K_DIM + c0i;
  const int8_t* b_g1 = B + (size_t)(n0 + r1i) * K_DIM + c0i;
  int8_t* a_l0 = lds_a + (size_t)tid * 16;
  int8_t* a_l1 = lds_a + (size_t)(tid + 256) * 16;
  int8_t* b_l0 = lds_b + (size_t)tid * 16;
  int8_t* b_l1 = lds_b + (size_t)(tid + 256) * 16;

  const v4i* A4 = (const v4i*)lds_a;  // 16-byte units: idx = row*4 + quad
  const v4i* B4 = (const v4i*)lds_b;

  v4i acc[4][4] = {};

  for (int k0 = 0; k0 < K_DIM; k0 += BK) {
    load_lds16(a_g0, a_l0);
    load_lds16(a_g1, a_l1);
    load_lds16(b_g0, b_l0);
    load_lds16(b_g1, b_l1);
    a_g0 += BK; a_g1 += BK; b_g0 += BK; b_g1 += BK;
    __syncthreads();

    v4i af[4], bf[4];
#pragma unroll
    for (int i = 0; i < 4; ++i)
      af[i] = A4[(wm * 64 + i * 16 + lrow) * 4 + quad];
#pragma unroll
    for (int j = 0; j < 4; ++j)
      bf[j] = B4[(wn * 64 + j * 16 + lrow) * 4 + quad];

#pragma unroll
    for (int i = 0; i < 4; ++i)
#pragma unroll
      for (int j = 0; j < 4; ++j)
        acc[i][j] = __builtin_amdgcn_mfma_i32_16x16x64_i8(af[i], bf[j],
                                                          acc[i][j], 0, 0, 0);
    __syncthreads();
  }

  // Epilogue: y = 0.01 * acc + bias[n]
#pragma unroll
  for (int j = 0; j < 4; ++j) {
    const int n = n0 + wn * 64 + j * 16 + lrow;
    const float bn = bias[n];
#pragma unroll
    for (int i = 0; i < 4; ++i) {
      const int mb = m0 + wm * 64 + i * 16 + quad * 4;
#pragma unroll
      for (int r = 0; r < 4; ++r)
        C[(size_t)(mb + r) * N_DIM + n] = 0.01f * (float)acc[i][j][r] + bn;
    }
  }
}

extern "C" void kernel_launch(void* const* d_in, const int* in_sizes, int n_in,
                              void* d_out, int out_size, void* d_ws, size_t ws_size,
                              hipStream_t stream) {
  const float* x    = (const float*)d_in[0];
  const int*   w32  = (const int*)d_in[1];   // harness stores int8 input as int32
  const float* bias = (const float*)d_in[2];
  float* out = (float*)d_out;
  const int M = in_sizes[0] / K_DIM;  // 8192

  int8_t* xq = (int8_t*)d_ws;                              // M*K   = 33.5 MB
  int8_t* wq = (int8_t*)d_ws + (size_t)M * K_DIM;          // N*K   = 16.8 MB

  const int nw4 = (N_DIM * K_DIM) / 4;
  pack_w_kernel<<<(nw4 + 255) / 256, 256, 0, stream>>>(w32, (uint32_t*)wq, nw4);

  const int n4 = (M * K_DIM) / 4;
  quant_kernel<<<(n4 + 255) / 256, 256, 0, stream>>>(x, (uint32_t*)xq, n4);

  dim3 grid(N_DIM / BN, M / BM);  // 32 x 64 = 2048 blocks
  gemm_i8_kernel<<<grid, 256, 0, stream>>>(xq, wq, bias, out, M);
}

// Round 3
// 401.587 us; speedup vs baseline: 1.0379x; 1.0379x over previous
//
#include <hip/hip_runtime.h>
#include <stdint.h>
#include <stddef.h>

#define K_DIM 4096
#define N_DIM 4096
#define BM 128
#define BN 128
#define BK 128   // bytes of K per barrier (halves barrier count vs BK=64)

typedef int v4i __attribute__((ext_vector_type(4)));
typedef uint32_t v4u __attribute__((ext_vector_type(4)));

__device__ __forceinline__ void load_lds16(const void* gp, void* lp) {
  __builtin_amdgcn_global_load_lds(
      (__attribute__((address_space(1))) void*)(uintptr_t)gp,
      (__attribute__((address_space(3))) void*)(uintptr_t)lp,
      16, 0, 0);
}

__device__ __forceinline__ uint32_t pack4(int a, int b, int c, int d) {
  return (uint32_t)(uint8_t)a | ((uint32_t)(uint8_t)b << 8) |
         ((uint32_t)(uint8_t)c << 16) | ((uint32_t)(uint8_t)d << 24);
}

// ---------------- Kernel 0: pack weight int32 -> int8 ----------------------
// Harness materializes integer inputs as int32; repack. 16 ints/thread:
// 4x int4 loads, one uint4 (16 B) store.
__global__ __launch_bounds__(256) void pack_w_kernel(
    const int4* __restrict__ w32, v4u* __restrict__ w8, int n16) {
  int i = blockIdx.x * 256 + threadIdx.x;
  if (i >= n16) return;
  int4 a = w32[i * 4 + 0], b = w32[i * 4 + 1], c = w32[i * 4 + 2], d = w32[i * 4 + 3];
  v4u o;
  o.x = pack4(a.x, a.y, a.z, a.w);
  o.y = pack4(b.x, b.y, b.z, b.w);
  o.z = pack4(c.x, c.y, c.z, c.w);
  o.w = pack4(d.x, d.y, d.z, d.w);
  w8[i] = o;
}

// ---------------- Kernel 1: quantize fp32 -> int8 --------------------------
// y = clip(rint(x / 0.05f), -128, 127); exact fp32 division + RNE to match
// jnp.round(x / INPUT_SCALE). 16 floats/thread -> one 16 B store.
__global__ __launch_bounds__(256) void quant_kernel(
    const float4* __restrict__ x, v4u* __restrict__ xq, int n16) {
  int i = blockIdx.x * 256 + threadIdx.x;
  if (i >= n16) return;
  v4u o;
#pragma unroll
  for (int j = 0; j < 4; ++j) {
    float4 v = x[i * 4 + j];
    float r0 = fminf(fmaxf(rintf(v.x / 0.05f), -128.f), 127.f);
    float r1 = fminf(fmaxf(rintf(v.y / 0.05f), -128.f), 127.f);
    float r2 = fminf(fmaxf(rintf(v.z / 0.05f), -128.f), 127.f);
    float r3 = fminf(fmaxf(rintf(v.w / 0.05f), -128.f), 127.f);
    o[j] = pack4((int)r0, (int)r1, (int)r2, (int)r3);
  }
  xq[i] = o;
}

// ---------------- Kernel 2: int8 GEMM, A[M,K] x B[N,K]^T -------------------
// 128x128 tile, BK=128, 4 waves in 2x2 (wave tile 64x64), 2 K-substeps of
// 16x v_mfma_i32_16x16x64_i8 each. global_load_lds width=16 staging.
//
// LDS layout (XOR-swizzled): element block (row, kv) [kv = 16-byte K-chunk
// 0..7] lives at v4i index row*8 + (kv ^ (row&7)). The swizzle balances all
// 32 banks for the fragment reads (naive BK=128 layout uses only 16 banks
// per quad). Staging achieves the swizzle by permuting the per-lane GLOBAL
// source addresses (global_load_lds LDS dst is rigid: base + lane*16).
//
// A-frag (lane l): A[m=l&15][k=s*64+(l>>4)*16 ..+16)  -> swizzled ds_read_b128
// C/D: col = lane&15, row = (lane>>4)*4 + reg (dtype-independent, m121-m128)
//
// Grid swizzle: bid -> xcd = bid&7 (consecutive blocks round-robin XCDs);
// each XCD owns 4 N-blocks (2 MB of B, L2-resident) and sweeps M; A panel
// reused across the 4 n-neighbors via L2.
__global__ __launch_bounds__(256) void gemm_i8_kernel(
    const int8_t* __restrict__ A,     // [M, K] quantized activations
    const int8_t* __restrict__ B,     // [N, K] weight (packed int8)
    const float* __restrict__ bias,   // [N]
    float* __restrict__ C,            // [M, N]
    int M) {
  __shared__ __align__(16) int8_t lds_a[BM * BK];  // 16 KB
  __shared__ __align__(16) int8_t lds_b[BN * BK];  // 16 KB

  const int tid  = threadIdx.x;
  const int lane = tid & 63;
  const int wave = tid >> 6;
  const int wm   = wave >> 1;
  const int wn   = wave & 1;
  const int quad = lane >> 4;
  const int lrow = lane & 15;

  // XCD-aware block swizzle: 4 N-blocks per XCD.
  const int bid   = blockIdx.x;
  const int xcd   = bid & 7;
  const int slot  = bid >> 3;
  const int n_blk = xcd * 4 + (slot & 3);
  const int m_blk = slot >> 2;
  const int m0 = m_blk * BM;
  const int n0 = n_blk * BN;

  // Staging geometry: tile = 128 rows x 8 kv-chunks = 1024 chunks of 16 B.
  // Issue q (0..3): chunk c = q*256 + tid; LDS dst = c*16;
  // global src: row = c>>3, src kv = (c&7) ^ (row&7)  [swizzle inverse].
  int a_row[4], a_col[4];
#pragma unroll
  for (int q = 0; q < 4; ++q) {
    int c = q * 256 + tid;
    a_row[q] = c >> 3;
    a_col[q] = (((c & 7) ^ ((c >> 3) & 7)) << 4);
  }
  const int8_t* ag[4];
  const int8_t* bg[4];
#pragma unroll
  for (int q = 0; q < 4; ++q) {
    ag[q] = A + (size_t)(m0 + a_row[q]) * K_DIM + a_col[q];
    bg[q] = B + (size_t)(n0 + a_row[q]) * K_DIM + a_col[q];
  }

  const v4i* A4 = (const v4i*)lds_a;  // v4i index = row*8 + kv_phys
  const v4i* B4 = (const v4i*)lds_b;
  const int rx7 = lrow & 7;           // row&7 for all this lane's frag rows

  v4i acc[4][4] = {};

  for (int k0 = 0; k0 < K_DIM; k0 += BK) {
#pragma unroll
    for (int q = 0; q < 4; ++q) {
      load_lds16(ag[q], lds_a + (size_t)(q * 256 + tid) * 16);
      load_lds16(bg[q], lds_b + (size_t)(q * 256 + tid) * 16);
      ag[q] += BK; bg[q] += BK;
    }
    __syncthreads();

#pragma unroll
    for (int s = 0; s < 2; ++s) {
      const int kv = (s * 4 + quad) ^ rx7;  // swizzled 16B K-chunk
      v4i af[4], bf[4];
#pragma unroll
      for (int i = 0; i < 4; ++i)
        af[i] = A4[(wm * 64 + i * 16 + lrow) * 8 + kv];
#pragma unroll
      for (int j = 0; j < 4; ++j)
        bf[j] = B4[(wn * 64 + j * 16 + lrow) * 8 + kv];
#pragma unroll
      for (int i = 0; i < 4; ++i)
#pragma unroll
        for (int j = 0; j < 4; ++j)
          acc[i][j] = __builtin_amdgcn_mfma_i32_16x16x64_i8(af[i], bf[j],
                                                            acc[i][j], 0, 0, 0);
    }
    __syncthreads();
  }

  // Epilogue: y = 0.01 * acc + bias[n]
#pragma unroll
  for (int j = 0; j < 4; ++j) {
    const int n = n0 + wn * 64 + j * 16 + lrow;
    const float bn = bias[n];
#pragma unroll
    for (int i = 0; i < 4; ++i) {
      const int mb = m0 + wm * 64 + i * 16 + quad * 4;
#pragma unroll
      for (int r = 0; r < 4; ++r)
        C[(size_t)(mb + r) * N_DIM + n] = 0.01f * (float)acc[i][j][r] + bn;
    }
  }
}

extern "C" void kernel_launch(void* const* d_in, const int* in_sizes, int n_in,
                              void* d_out, int out_size, void* d_ws, size_t ws_size,
                              hipStream_t stream) {
  const float* x    = (const float*)d_in[0];
  const int*   w32  = (const int*)d_in[1];   // harness stores int8 input as int32
  const float* bias = (const float*)d_in[2];
  float* out = (float*)d_out;
  const int M = in_sizes[0] / K_DIM;  // 8192

  int8_t* xq = (int8_t*)d_ws;                              // M*K = 33.5 MB
  int8_t* wq = (int8_t*)d_ws + (size_t)M * K_DIM;          // N*K = 16.8 MB

  const int nw16 = (N_DIM * K_DIM) / 16;
  pack_w_kernel<<<(nw16 + 255) / 256, 256, 0, stream>>>(
      (const int4*)w32, (v4u*)wq, nw16);

  const int n16 = (M * K_DIM) / 16;
  quant_kernel<<<(n16 + 255) / 256, 256, 0, stream>>>(
      (const float4*)x, (v4u*)xq, n16);

  const int nblocks = (M / BM) * (N_DIM / BN);  // 2048
  gemm_i8_kernel<<<nblocks, 256, 0, stream>>>(xq, wq, bias, out, M);
}